// Round 13
// baseline (624.538 us; speedup 1.0000x reference)
//
#include <hip/hip_runtime.h>

// ---------------------------------------------------------------------------
// Sizes (fixed): B=8, C=dm=256, H=W=64, N=4096
// ws (ushort units):
//   xt_pad [8][4224][256] bf16   (row 0 <-> n=-64; 64-row zero halos)
//   wt3    [9][512][256]  bf16   (k=(tap,ci), co-major rows)
//   wt1    [1][256][256]  bf16
//   q_t    [8][4096][256] bf16 token-major (1/16 * log2e folded)
//   k_t    [8][4096][256] bf16 token-major
//   v_t    [8][256][4096] bf16 NCHW
//   gstat float[512] (BN sum/sumsq accumulators)
// d_out: y = r + xc (NCHW fp32), BN applied in place.
// ---------------------------------------------------------------------------

typedef __attribute__((ext_vector_type(8))) short bf16x8;
typedef __attribute__((ext_vector_type(4))) float f32x4;
typedef __attribute__((ext_vector_type(16))) float f32x16;
typedef __attribute__((ext_vector_type(8))) unsigned short u16x8;

__device__ inline unsigned short f2bf(float f) {
  union { float f; unsigned u; } c; c.f = f;
  unsigned u = c.u;
  return (unsigned short)((u + 0x7fffu + ((u >> 16) & 1u)) >> 16);  // RNE
}

__device__ inline unsigned cvtpk(float lo, float hi) {
  unsigned r;
  asm("v_cvt_pk_bf16_f32 %0, %1, %2" : "=v"(r) : "v"(lo), "v"(hi));
  return r;
}

// async global->LDS DMA, 16 B per lane; dest = wave-uniform base (+lane*16 HW)
__device__ inline void dma16(const void* g, void* l) {
  __builtin_amdgcn_global_load_lds(
      (const __attribute__((address_space(1))) unsigned int*)g,
      (__attribute__((address_space(3))) unsigned int*)l, 16, 0, 0);
}

// ---------------- K1: transpose + cast x -> xt_pad (and zero halos) --------
__global__ __launch_bounds__(256) void k_xt(
    const float* __restrict__ x, ushort* __restrict__ xt)
{
  const int b = blockIdx.z, ci0 = blockIdx.y * 64, gx = blockIdx.x;
  const int t = threadIdx.x;
  ushort* img = xt + (size_t)b * 4224 * 256;  // row 0 == n=-64
  if (gx >= 64) {  // zero halos
    int r0 = (gx == 64) ? 0 : 4160;
#pragma unroll
    for (int k = 0; k < 2; ++k) {
      int idx = t + k * 256;
      int r = idx >> 3, u = idx & 7;
      u16x8 z = (u16x8)0;
      *(u16x8*)&img[(size_t)(r0 + r) * 256 + ci0 + u * 8] = z;
    }
    return;
  }
  const int n0 = gx * 64;
  __shared__ ushort tl[64][65];
  {
    const float* xb = x + ((size_t)b * 256 + ci0) * 4096 + n0;
    int i = t >> 2, j0 = (t & 3) * 16;
#pragma unroll
    for (int jj = 0; jj < 16; jj += 4) {
      float4 v = *(const float4*)&xb[(size_t)i * 4096 + j0 + jj];
      tl[j0 + jj + 0][i] = f2bf(v.x);
      tl[j0 + jj + 1][i] = f2bf(v.y);
      tl[j0 + jj + 2][i] = f2bf(v.z);
      tl[j0 + jj + 3][i] = f2bf(v.w);
    }
  }
  __syncthreads();
  {
    int j = t >> 3, u = t & 7;
#pragma unroll
    for (int k = 0; k < 2; ++k) {
      int jr = j + k * 32;
      ushort tmp[8];
#pragma unroll
      for (int e = 0; e < 8; ++e) tmp[e] = tl[jr][u * 8 + e];
      *(u16x8*)&img[(size_t)(64 + n0 + jr) * 256 + ci0 + u * 8] = *(u16x8*)tmp;
    }
  }
}

// ---------------- K2: weight prep: w[co][ci][taps] f32 -> wt[tap][co][ci] --
__global__ __launch_bounds__(256) void k_wprep(
    const float* __restrict__ w, ushort* __restrict__ wt, int ntaps, int nco)
{
  const int co = blockIdx.x;
  const int t = threadIdx.x;
  __shared__ float ws[2304];
  const int tot = 256 * ntaps;
  for (int i = t; i < tot; i += 256) ws[i] = w[(size_t)co * tot + i];
  __syncthreads();
  for (int tap = 0; tap < ntaps; ++tap)
    wt[((size_t)tap * nco + co) * 256 + t] = f2bf(ws[t * ntaps + tap]);
}

// ---------------- K3: implicit-GEMM conv via bf16 MFMA, dma16 pipelined ----
__global__ __launch_bounds__(256, 2) void k_conv(
    const ushort* __restrict__ xt, const ushort* __restrict__ wt,
    const float* __restrict__ bias, ushort* __restrict__ outT,
    ushort* __restrict__ outV, int ntaps, int nco, float oscale)
{
  extern __shared__ unsigned char smem[];
  ushort* As0 = (ushort*)smem;                    // 258*32*2 = 16512 B
  ushort* As1 = (ushort*)(smem + 16512);
  ushort* Bs0 = (ushort*)(smem + 33024);          // 256*32*2 = 16384 B
  ushort* Bs1 = (ushort*)(smem + 33024 + 16384);  // total 65792 B
  __shared__ float bias_s[256];

  const int t = threadIdx.x, lane = t & 63;
  const int wv = t >> 6, wm = wv >> 1, wn = wv & 1;
  const int qc = lane & 15, grp = lane >> 4;
  const int b = blockIdx.z, n0 = blockIdx.x * 128, co0 = blockIdx.y * 256;
  const bool nchw = (outV != nullptr) && (blockIdx.y == 1);
  const ushort* img = xt + (size_t)b * 4224 * 256 + (size_t)64 * 256;  // n=0
  const int wbase = t & ~63;

  bias_s[t] = bias[co0 + t];

  f32x4 acc[4][8];
#pragma unroll
  for (int mi = 0; mi < 4; ++mi)
#pragma unroll
    for (int ni = 0; ni < 8; ++ni) acc[mi][ni] = f32x4{0.f, 0.f, 0.f, 0.f};

  auto stageA = [&](int c8, ushort* dst) {
    const int ci0 = c8 * 32;
#pragma unroll
    for (int k = 0; k < 5; ++k) {
      int idx = k * 256 + t;
      if (idx < 1032) {
        int r = idx >> 2, u = idx & 3;
        int n = min(max(n0 + r - 65, -64), 4159);
        dma16(img + (size_t)n * 256 + ci0 + u * 8,
              dst + (size_t)(k * 256 + wbase) * 8);
      }
    }
  };
  auto stageB = [&](int tap, int c8, ushort* dst) {
    const ushort* wrow = wt + ((size_t)tap * nco + co0) * 256 + c8 * 32;
#pragma unroll
    for (int k = 0; k < 4; ++k) {
      int idx = k * 256 + t;
      int r = idx >> 2, u = idx & 3;
      dma16(wrow + (size_t)r * 256 + u * 8,
            dst + (size_t)(k * 256 + wbase) * 8);
    }
  };

  stageA(0, As0);
  stageB(0, 0, Bs0);
  asm volatile("s_waitcnt vmcnt(0)" ::: "memory");
  __syncthreads();

  const int niters = 8 * ntaps;
  int iter = 0;
  for (int c8 = 0; c8 < 8; ++c8) {
    const ushort* Asb = (c8 & 1) ? As1 : As0;
    for (int tap = 0; tap < ntaps; ++tap, ++iter) {
      const ushort* Bsb = (iter & 1) ? Bs1 : Bs0;
      if (iter + 1 < niters) {
        int ntap = (tap + 1 == ntaps) ? 0 : tap + 1;
        int nc8  = (tap + 1 == ntaps) ? c8 + 1 : c8;
        stageB(ntap, nc8, (iter & 1) ? Bs0 : Bs1);
        if (ntap == 0) stageA(nc8, (c8 & 1) ? As0 : As1);
      }
      const int dy = (ntaps == 9) ? (tap / 3 - 1) : 0;
      const int dx = (ntaps == 9) ? (tap % 3 - 1) : 0;
      const int off = dy * 64 + dx;
      bf16x8 bf[8];
#pragma unroll
      for (int ni = 0; ni < 8; ++ni)
        bf[ni] = *(const bf16x8*)&Bsb[(wn * 128 + ni * 16 + qc) * 32 + grp * 8];
#pragma unroll
      for (int mi = 0; mi < 4; ++mi) {
        int ar = wm * 64 + mi * 16 + qc + off + 65;
        bf16x8 af = *(const bf16x8*)&Asb[ar * 32 + grp * 8];
        if (dx < 0 && mi == 0 && qc == 0)  af = (bf16x8)0;  // w==0 edge
        if (dx > 0 && mi == 3 && qc == 15) af = (bf16x8)0;  // w==63 edge
#pragma unroll
        for (int ni = 0; ni < 8; ++ni)
          acc[mi][ni] = __builtin_amdgcn_mfma_f32_16x16x32_bf16(af, bf[ni], acc[mi][ni], 0, 0, 0);
      }
      asm volatile("s_waitcnt vmcnt(0)" ::: "memory");
      __syncthreads();
    }
  }

  if (!nchw) {
    ushort (*olds)[264] = (ushort(*)[264])smem;
#pragma unroll
    for (int mi = 0; mi < 4; ++mi) {
      int p = wm * 64 + mi * 16 + grp * 4;
#pragma unroll
      for (int ni = 0; ni < 8; ++ni) {
        int c = wn * 128 + ni * 16 + qc;
        float bv = bias_s[c];
#pragma unroll
        for (int r = 0; r < 4; ++r)
          olds[p + r][c] = f2bf(fmaxf(acc[mi][ni][r] + bv, 0.f) * oscale);
      }
    }
    __syncthreads();
    ushort* dst = outT + ((size_t)b * 4096 + n0) * 256;
#pragma unroll
    for (int k = 0; k < 16; ++k) {
      int idx = t + k * 256;
      int r = idx >> 5, u = idx & 31;
      *(u16x8*)&dst[(size_t)r * 256 + u * 8] = *(const u16x8*)&olds[r][u * 8];
    }
  } else {
    ushort (*oldsT)[136] = (ushort(*)[136])smem;
#pragma unroll
    for (int mi = 0; mi < 4; ++mi) {
      int p = wm * 64 + mi * 16 + grp * 4;
#pragma unroll
      for (int ni = 0; ni < 8; ++ni) {
        int c = wn * 128 + ni * 16 + qc;
        float bv = bias_s[c];
        ushort4 pk;
        pk.x = f2bf(fmaxf(acc[mi][ni][0] + bv, 0.f) * oscale);
        pk.y = f2bf(fmaxf(acc[mi][ni][1] + bv, 0.f) * oscale);
        pk.z = f2bf(fmaxf(acc[mi][ni][2] + bv, 0.f) * oscale);
        pk.w = f2bf(fmaxf(acc[mi][ni][3] + bv, 0.f) * oscale);
        *(ushort4*)&oldsT[c][p] = pk;
      }
    }
    __syncthreads();
    ushort* dst = outV + (size_t)b * 256 * 4096 + n0;
#pragma unroll
    for (int k = 0; k < 16; ++k) {
      int idx = t + k * 256;
      int c = idx >> 4, u = idx & 15;
      *(u16x8*)&dst[(size_t)c * 4096 + u * 8] = *(const u16x8*)&oldsT[c][u * 8];
    }
  }
}

// ---------------- K4: 32x32 MFMA split-K flash attention -------------------
// 512 thr = 8 waves = 2 waves/SIMD. Group g=w>>2 owns key half [g*2048) in
// KVBLK=32 tiles; wg=w&3 owns 32 q (QBLK=128). Per-group double-buffered DMA
// staging, ONE barrier/tile. Per-wave: o[8] f32x16 + qf[16] ~ 230 VGPR < 256
// cap (round-6 lesson: state must fit). QK: mfma_32x32x16, S^T layout
// col=q=lane&31, row=key=(r&3)+8*(r>>2)+4*gK [m74/m101]. P packed in-register
// via cvtpk+permlane32_swap (HW-verified round 12). Merge: per-q32 (m,l,o)
// exchange through LDS (round-5 lesson).
// LDS: K 4x16K @0 | V 4x16K @65536 = 128K; epilogue obuf+mlbuf+part 139264.
__global__ __launch_bounds__(512, 2) void k_attn(
    const ushort* __restrict__ q_t, const ushort* __restrict__ k_t,
    const ushort* __restrict__ v_t, const float* __restrict__ x,
    float* __restrict__ y, float* __restrict__ gstat)
{
  extern __shared__ unsigned char smem[];
  const int tid = threadIdx.x, lane = tid & 63, w = tid >> 6;
  const int g = w >> 2, wg = w & 3, tg = tid & 255;
  const int q32 = lane & 31, gK = lane >> 5, swz = q32 & 7;
  const int b = blockIdx.y, q0 = blockIdx.x * 128;

  ushort* kbf[2] = { (ushort*)(smem + g * 32768),
                     (ushort*)(smem + g * 32768 + 16384) };
  ushort* vbf[2] = { (ushort*)(smem + 65536 + g * 32768),
                     (ushort*)(smem + 65536 + g * 32768 + 16384) };

  // per-lane DMA source offsets (ushort units); swizzles match LDS reads
  int offk[4], offv[4];
#pragma unroll
  for (int k = 0; k < 4; ++k) {
    int i = k * 256 + tg;
    int j = i >> 5, s = i & 31;                 // K: 32 rows x 32 granules
    offk[k] = j * 256 + ((s ^ (j & 7)) << 3);
    int d = i >> 2, s2 = i & 3;                 // V: 256 rows x 4 granules
    offv[k] = d * 4096 + ((s2 ^ (d & 3)) << 3);
  }
  const ushort* kT = k_t + ((size_t)b * 4096 + g * 2048) * 256;
  const ushort* vT = v_t + (size_t)b * 256 * 4096 + g * 2048;

  // Q^T fragments, resident: qf[ds] elem j = Q[q32][ds*16 + gK*8 + j]
  bf16x8 qf[16];
  {
    const ushort* qrow =
        q_t + ((size_t)b * 4096 + q0 + wg * 32 + q32) * 256 + gK * 8;
#pragma unroll
    for (int ds = 0; ds < 16; ++ds)
      qf[ds] = *(const bf16x8*)&qrow[ds * 16];
  }

  f32x16 o[8];
#pragma unroll
  for (int db = 0; db < 8; ++db) o[db] = (f32x16)0.f;
  float m_run = -1e30f, lp = 0.f;

  auto stage = [&](const ushort* kp, const ushort* vp, ushort* kb, ushort* vb) {
#pragma unroll
    for (int k = 0; k < 4; ++k)
      dma16(kp + offk[k], kb + (size_t)(k * 256 + wg * 64) * 8);
#pragma unroll
    for (int k = 0; k < 4; ++k)
      dma16(vp + offv[k], vb + (size_t)(k * 256 + wg * 64) * 8);
  };

  stage(kT, vT, kbf[0], vbf[0]);
  kT += 8192; vT += 32;
  asm volatile("s_waitcnt vmcnt(0)" ::: "memory");
  __syncthreads();

  // precomputed LDS read columns (ushort offsets within a row)
  int kcol[16], vcol[2];
#pragma unroll
  for (int ds = 0; ds < 16; ++ds) kcol[ds] = ((2 * ds + gK) ^ swz) << 3;
#pragma unroll
  for (int ks = 0; ks < 2; ++ks) vcol[ks] = ((2 * ks + gK) ^ (q32 & 3)) << 3;
  const int krow = q32 * 256;

  for (int t = 0; t < 64; ++t) {
    ushort* kb = kbf[t & 1];
    ushort* vb = vbf[t & 1];
    if (t < 63) {
      stage(kT, vT, kbf[(t + 1) & 1], vbf[(t + 1) & 1]);
      kT += 8192; vT += 32;
    }

    // ---- S^T = K * Q^T : one 32-key block, 16 chained k-steps ----
    f32x16 s0 = (f32x16)0.f;
    __builtin_amdgcn_s_setprio(1);
#pragma unroll
    for (int ds = 0; ds < 16; ++ds) {
      bf16x8 a0 = *(const bf16x8*)&kb[krow + kcol[ds]];
      s0 = __builtin_amdgcn_mfma_f32_32x32x16_bf16(a0, qf[ds], s0, 0, 0, 0);
    }
    __builtin_amdgcn_s_setprio(0);

    // ---- online softmax (exp2 domain, defer-max, deferred l) ----
    float pmax;
    {
      float m0 = fmaxf(fmaxf(s0[0], s0[1]), fmaxf(s0[2], s0[3]));
      m0 = fmaxf(m0, fmaxf(fmaxf(s0[4], s0[5]), fmaxf(s0[6], s0[7])));
      m0 = fmaxf(m0, fmaxf(fmaxf(s0[8], s0[9]), fmaxf(s0[10], s0[11])));
      m0 = fmaxf(m0, fmaxf(fmaxf(s0[12], s0[13]), fmaxf(s0[14], s0[15])));
      pmax = m0;
    }
    pmax = fmaxf(pmax, __shfl_xor(pmax, 32));  // lanes l,l^32 share q
    if (pmax - m_run > 11.5f) {
      float mn = fmaxf(m_run, pmax);
      float al = exp2f(m_run - mn);
      m_run = mn; lp *= al;
#pragma unroll
      for (int db = 0; db < 8; ++db) o[db] *= al;
    }
    float p0[16];
#pragma unroll
    for (int r = 0; r < 16; ++r) {
      p0[r] = exp2f(s0[r] - m_run);
      lp += p0[r];
    }

    // ---- pack P into PV B-fragments via cvt_pk + permlane32_swap ----
    bf16x8 pB[2];
    {
      unsigned a0 = cvtpk(p0[0], p0[1]),  a1 = cvtpk(p0[2], p0[3]);
      unsigned a2 = cvtpk(p0[4], p0[5]),  a3 = cvtpk(p0[6], p0[7]);
      unsigned a4 = cvtpk(p0[8], p0[9]),  a5 = cvtpk(p0[10], p0[11]);
      unsigned a6 = cvtpk(p0[12], p0[13]), a7 = cvtpk(p0[14], p0[15]);
      asm volatile("v_permlane32_swap_b32 %0, %1" : "+v"(a0), "+v"(a2));
      asm volatile("v_permlane32_swap_b32 %0, %1" : "+v"(a1), "+v"(a3));
      asm volatile("v_permlane32_swap_b32 %0, %1" : "+v"(a4), "+v"(a6));
      asm volatile("v_permlane32_swap_b32 %0, %1" : "+v"(a5), "+v"(a7));
      union { unsigned u[4]; bf16x8 v; } f0, f1;
      f0.u[0] = a0; f0.u[1] = a1; f0.u[2] = a2; f0.u[3] = a3;
      f1.u[0] = a4; f1.u[1] = a5; f1.u[2] = a6; f1.u[3] = a7;
      pB[0] = f0.v; pB[1] = f1.v;
    }

    // ---- r^T += V^T * P : 8 d-blocks x 2 key-steps ----
    __builtin_amdgcn_s_setprio(1);
#pragma unroll
    for (int db = 0; db < 8; ++db) {
      const int vbase = (db * 32 + q32) * 32;
      bf16x8 va0 = *(const bf16x8*)&vb[vbase + vcol[0]];
      bf16x8 va1 = *(const bf16x8*)&vb[vbase + vcol[1]];
      o[db] = __builtin_amdgcn_mfma_f32_32x32x16_bf16(va0, pB[0], o[db], 0, 0, 0);
      o[db] = __builtin_amdgcn_mfma_f32_32x32x16_bf16(va1, pB[1], o[db], 0, 0, 0);
    }
    __builtin_amdgcn_s_setprio(0);

    asm volatile("s_waitcnt vmcnt(0)" ::: "memory");
    __syncthreads();  // next tile's DMA landed; buffers swappable
  }

  // ---- merge groups (per-q32 state!), residual + NCHW store, BN partials --
  lp += __shfl_xor(lp, 32);

  float2* mlbuf = (float2*)(smem + 135168);      // [8 waves][32 q]
  float* part1  = (float*)(smem + 137216);       // [256]
  float* part2  = (float*)(smem + 138240);       // [256]
  if (gK == 0) mlbuf[w * 32 + q32] = make_float2(m_run, lp);
  __syncthreads();
  float2 mp = mlbuf[(w ^ 4) * 32 + q32];
  float mF = fmaxf(m_run, mp.x);
  float aS = exp2f(m_run - mF);
  float lf = lp * aS + mp.y * exp2f(mp.x - mF);
  float inv = 1.f / lf;

  float (*obuf)[132] = (float(*)[132])smem;      // [256 d][128 q + pad]
  if (g == 1) {
#pragma unroll
    for (int db = 0; db < 8; ++db)
#pragma unroll
      for (int r = 0; r < 16; ++r) {
        int d = db * 32 + (r & 3) + 8 * (r >> 2) + 4 * gK;
        obuf[d][wg * 32 + q32] = o[db][r] * aS;
      }
  }
  __syncthreads();
  if (g == 0) {
#pragma unroll
    for (int db = 0; db < 8; ++db)
#pragma unroll
      for (int r = 0; r < 16; ++r) {
        int d = db * 32 + (r & 3) + 8 * (r >> 2) + 4 * gK;
        obuf[d][wg * 32 + q32] =
            (o[db][r] * aS + obuf[d][wg * 32 + q32]) * inv;
      }
  }
  __syncthreads();

  const float* xb = x + (size_t)b * 256 * 4096 + q0;
  float*       yb = y + (size_t)b * 256 * 4096 + q0;
#pragma unroll
  for (int k = 0; k < 16; ++k) {
    int i = tid + k * 512;
    int c = i >> 5, f4 = (i & 31) << 2;
    float4 xr4 = *(const float4*)&xb[(size_t)c * 4096 + f4];
    float4 rv = *(const float4*)&obuf[c][f4];
    rv.x += xr4.x; rv.y += xr4.y; rv.z += xr4.z; rv.w += xr4.w;
    *(float4*)&yb[(size_t)c * 4096 + f4] = rv;
    // BN partials: c uniform across each 32-lane group -> butterfly, then
    // lane0 plain-stores part[c] (each (group,k) owns a unique c).
    float ls1 = (rv.x + rv.y) + (rv.z + rv.w);
    float ls2 = (rv.x * rv.x + rv.y * rv.y) + (rv.z * rv.z + rv.w * rv.w);
#pragma unroll
    for (int sh = 1; sh <= 16; sh <<= 1) {
      ls1 += __shfl_xor(ls1, sh);
      ls2 += __shfl_xor(ls2, sh);
    }
    if ((tid & 31) == 0) { part1[c] = ls1; part2[c] = ls2; }
  }
  __syncthreads();
  if (tid < 256) {
    atomicAdd(&gstat[tid], part1[tid]);
    atomicAdd(&gstat[256 + tid], part2[tid]);
  }
}

// ---------------- K5: BN finalize + apply in place (fused) -----------------
__global__ __launch_bounds__(256) void k_bnapply(
    float* __restrict__ y, const float* __restrict__ gstat,
    const float* __restrict__ gamma, const float* __restrict__ beta)
{
  __shared__ float sc_s[256], sh_s[256];
  {
    const int c = threadIdx.x;
    float mean = gstat[c] * (1.f / 32768.f);
    float var  = gstat[256 + c] * (1.f / 32768.f) - mean * mean;
    float inv  = rsqrtf(var + 1e-5f);
    float g = gamma[c] * inv;
    sc_s[c] = g;
    sh_s[c] = beta[c] - mean * g;
  }
  __syncthreads();
  const int total4 = 8 * 256 * 1024;
  for (int i = blockIdx.x * 256 + threadIdx.x; i < total4; i += gridDim.x * 256) {
    int c = (i >> 10) & 255;
    float sc = sc_s[c], sh = sh_s[c];
    float4 v = ((const float4*)y)[i];
    v.x = fmaf(v.x, sc, sh);
    v.y = fmaf(v.y, sc, sh);
    v.z = fmaf(v.z, sc, sh);
    v.w = fmaf(v.w, sc, sh);
    ((float4*)y)[i] = v;
  }
}

// ---------------------------------------------------------------------------
extern "C" void kernel_launch(void* const* d_in, const int* in_sizes, int n_in,
                              void* d_out, int out_size, void* d_ws, size_t ws_size,
                              hipStream_t stream) {
  const float* x     = (const float*)d_in[0];
  const float* wq    = (const float*)d_in[1];
  const float* bq    = (const float*)d_in[2];
  const float* wkv   = (const float*)d_in[3];
  const float* bkv   = (const float*)d_in[4];
  const float* gamma = (const float*)d_in[5];
  const float* beta  = (const float*)d_in[6];
  float* out = (float*)d_out;

  ushort* xt  = (ushort*)d_ws;            // 8*4224*256 = 8650752
  ushort* wt3 = xt  + (size_t)8650752;    // 9*512*256 = 1179648
  ushort* wt1 = wt3 + (size_t)1179648;    // 256*256   = 65536
  ushort* q_t = wt1 + (size_t)65536;      // 8388608
  ushort* k_t = q_t + (size_t)8388608;
  ushort* v_t = k_t + (size_t)8388608;
  float* gstat = (float*)(v_t + (size_t)8388608);  // 512 floats

  hipMemsetAsync(gstat, 0, 2048, stream);

  k_xt<<<dim3(66, 4, 8), 256, 0, stream>>>(x, xt);
  k_wprep<<<dim3(512), 256, 0, stream>>>(wkv, wt3, 9, 512);
  k_wprep<<<dim3(256), 256, 0, stream>>>(wq, wt1, 1, 256);

  const int conv_smem = 69632;
  hipFuncSetAttribute(reinterpret_cast<const void*>(k_conv),
                      hipFuncAttributeMaxDynamicSharedMemorySize, conv_smem);
  // q = relu(conv1x1) * (1/16 * log2e) -> token-major (exp2-domain softmax)
  k_conv<<<dim3(32, 1, 8), 256, conv_smem, stream>>>(
      xt, wt1, bq, q_t, nullptr, 1, 256, 0.0625f * 1.44269504f);
  k_conv<<<dim3(32, 2, 8), 256, conv_smem, stream>>>(
      xt, wt3, bkv, k_t, v_t, 9, 512, 1.0f);

  const int attn_smem = 139264;  // main loop 128K; epilogue obuf+ml+part
  hipFuncSetAttribute(reinterpret_cast<const void*>(k_attn),
                      hipFuncAttributeMaxDynamicSharedMemorySize, attn_smem);
  k_attn<<<dim3(32, 8), 512, attn_smem, stream>>>(q_t, k_t, v_t, x, out, gstat);

  k_bnapply<<<dim3(2048), 256, 0, stream>>>(out, gstat, gamma, beta);
}

// Round 14
// 292.435 us; speedup vs baseline: 2.1356x; 2.1356x over previous
//
#include <hip/hip_runtime.h>

// ---------------------------------------------------------------------------
// Sizes (fixed): B=8, C=dm=256, H=W=64, N=4096
// ws (ushort units):
//   xt_pad [8][4224][256] bf16   (row 0 <-> n=-64; 64-row zero halos)
//   wt3    [9][512][256]  bf16   (k=(tap,ci), co-major rows)
//   wt1    [1][256][256]  bf16
//   q_t    [8][4096][256] bf16 token-major (1/16 * log2e folded)
//   k_t    [8][4096][256] bf16 token-major
//   v_t    [8][256][4096] bf16 NCHW
//   gstat float[512] (BN sum/sumsq accumulators)
// d_out: y = r + xc (NCHW fp32), BN applied in place.
// ---------------------------------------------------------------------------

typedef __attribute__((ext_vector_type(8))) short bf16x8;
typedef __attribute__((ext_vector_type(4))) float f32x4;
typedef __attribute__((ext_vector_type(8))) unsigned short u16x8;

__device__ inline unsigned short f2bf(float f) {
  union { float f; unsigned u; } c; c.f = f;
  unsigned u = c.u;
  return (unsigned short)((u + 0x7fffu + ((u >> 16) & 1u)) >> 16);  // RNE
}

__device__ inline unsigned cvtpk(float lo, float hi) {
  unsigned r;
  asm("v_cvt_pk_bf16_f32 %0, %1, %2" : "=v"(r) : "v"(lo), "v"(hi));
  return r;
}

// async global->LDS DMA, 16 B per lane; dest = wave-uniform base (+lane*16 HW)
__device__ inline void dma16(const void* g, void* l) {
  __builtin_amdgcn_global_load_lds(
      (const __attribute__((address_space(1))) unsigned int*)g,
      (__attribute__((address_space(3))) unsigned int*)l, 16, 0, 0);
}

// ---------------- K1: transpose + cast x -> xt_pad (and zero halos) --------
__global__ __launch_bounds__(256) void k_xt(
    const float* __restrict__ x, ushort* __restrict__ xt)
{
  const int b = blockIdx.z, ci0 = blockIdx.y * 64, gx = blockIdx.x;
  const int t = threadIdx.x;
  ushort* img = xt + (size_t)b * 4224 * 256;  // row 0 == n=-64
  if (gx >= 64) {  // zero halos
    int r0 = (gx == 64) ? 0 : 4160;
#pragma unroll
    for (int k = 0; k < 2; ++k) {
      int idx = t + k * 256;
      int r = idx >> 3, u = idx & 7;
      u16x8 z = (u16x8)0;
      *(u16x8*)&img[(size_t)(r0 + r) * 256 + ci0 + u * 8] = z;
    }
    return;
  }
  const int n0 = gx * 64;
  __shared__ ushort tl[64][65];
  {
    const float* xb = x + ((size_t)b * 256 + ci0) * 4096 + n0;
    int i = t >> 2, j0 = (t & 3) * 16;
#pragma unroll
    for (int jj = 0; jj < 16; jj += 4) {
      float4 v = *(const float4*)&xb[(size_t)i * 4096 + j0 + jj];
      tl[j0 + jj + 0][i] = f2bf(v.x);
      tl[j0 + jj + 1][i] = f2bf(v.y);
      tl[j0 + jj + 2][i] = f2bf(v.z);
      tl[j0 + jj + 3][i] = f2bf(v.w);
    }
  }
  __syncthreads();
  {
    int j = t >> 3, u = t & 7;
#pragma unroll
    for (int k = 0; k < 2; ++k) {
      int jr = j + k * 32;
      ushort tmp[8];
#pragma unroll
      for (int e = 0; e < 8; ++e) tmp[e] = tl[jr][u * 8 + e];
      *(u16x8*)&img[(size_t)(64 + n0 + jr) * 256 + ci0 + u * 8] = *(u16x8*)tmp;
    }
  }
}

// ---------------- K2: weight prep: w[co][ci][taps] f32 -> wt[tap][co][ci] --
__global__ __launch_bounds__(256) void k_wprep(
    const float* __restrict__ w, ushort* __restrict__ wt, int ntaps, int nco)
{
  const int co = blockIdx.x;
  const int t = threadIdx.x;
  __shared__ float ws[2304];
  const int tot = 256 * ntaps;
  for (int i = t; i < tot; i += 256) ws[i] = w[(size_t)co * tot + i];
  __syncthreads();
  for (int tap = 0; tap < ntaps; ++tap)
    wt[((size_t)tap * nco + co) * 256 + t] = f2bf(ws[t * ntaps + tap]);
}

// ---------------- K3: implicit-GEMM conv via bf16 MFMA, dma16 pipelined ----
__global__ __launch_bounds__(256, 2) void k_conv(
    const ushort* __restrict__ xt, const ushort* __restrict__ wt,
    const float* __restrict__ bias, ushort* __restrict__ outT,
    ushort* __restrict__ outV, int ntaps, int nco, float oscale)
{
  extern __shared__ unsigned char smem[];
  ushort* As0 = (ushort*)smem;                    // 258*32*2 = 16512 B
  ushort* As1 = (ushort*)(smem + 16512);
  ushort* Bs0 = (ushort*)(smem + 33024);          // 256*32*2 = 16384 B
  ushort* Bs1 = (ushort*)(smem + 33024 + 16384);  // total 65792 B
  __shared__ float bias_s[256];

  const int t = threadIdx.x, lane = t & 63;
  const int wv = t >> 6, wm = wv >> 1, wn = wv & 1;
  const int qc = lane & 15, grp = lane >> 4;
  const int b = blockIdx.z, n0 = blockIdx.x * 128, co0 = blockIdx.y * 256;
  const bool nchw = (outV != nullptr) && (blockIdx.y == 1);
  const ushort* img = xt + (size_t)b * 4224 * 256 + (size_t)64 * 256;  // n=0
  const int wbase = t & ~63;

  bias_s[t] = bias[co0 + t];

  f32x4 acc[4][8];
#pragma unroll
  for (int mi = 0; mi < 4; ++mi)
#pragma unroll
    for (int ni = 0; ni < 8; ++ni) acc[mi][ni] = f32x4{0.f, 0.f, 0.f, 0.f};

  auto stageA = [&](int c8, ushort* dst) {
    const int ci0 = c8 * 32;
#pragma unroll
    for (int k = 0; k < 5; ++k) {
      int idx = k * 256 + t;
      if (idx < 1032) {
        int r = idx >> 2, u = idx & 3;
        int n = min(max(n0 + r - 65, -64), 4159);
        dma16(img + (size_t)n * 256 + ci0 + u * 8,
              dst + (size_t)(k * 256 + wbase) * 8);
      }
    }
  };
  auto stageB = [&](int tap, int c8, ushort* dst) {
    const ushort* wrow = wt + ((size_t)tap * nco + co0) * 256 + c8 * 32;
#pragma unroll
    for (int k = 0; k < 4; ++k) {
      int idx = k * 256 + t;
      int r = idx >> 2, u = idx & 3;
      dma16(wrow + (size_t)r * 256 + u * 8,
            dst + (size_t)(k * 256 + wbase) * 8);
    }
  };

  stageA(0, As0);
  stageB(0, 0, Bs0);
  asm volatile("s_waitcnt vmcnt(0)" ::: "memory");
  __syncthreads();

  const int niters = 8 * ntaps;
  int iter = 0;
  for (int c8 = 0; c8 < 8; ++c8) {
    const ushort* Asb = (c8 & 1) ? As1 : As0;
    for (int tap = 0; tap < ntaps; ++tap, ++iter) {
      const ushort* Bsb = (iter & 1) ? Bs1 : Bs0;
      if (iter + 1 < niters) {
        int ntap = (tap + 1 == ntaps) ? 0 : tap + 1;
        int nc8  = (tap + 1 == ntaps) ? c8 + 1 : c8;
        stageB(ntap, nc8, (iter & 1) ? Bs0 : Bs1);
        if (ntap == 0) stageA(nc8, (c8 & 1) ? As0 : As1);
      }
      const int dy = (ntaps == 9) ? (tap / 3 - 1) : 0;
      const int dx = (ntaps == 9) ? (tap % 3 - 1) : 0;
      const int off = dy * 64 + dx;
      bf16x8 bf[8];
#pragma unroll
      for (int ni = 0; ni < 8; ++ni)
        bf[ni] = *(const bf16x8*)&Bsb[(wn * 128 + ni * 16 + qc) * 32 + grp * 8];
#pragma unroll
      for (int mi = 0; mi < 4; ++mi) {
        int ar = wm * 64 + mi * 16 + qc + off + 65;
        bf16x8 af = *(const bf16x8*)&Asb[ar * 32 + grp * 8];
        if (dx < 0 && mi == 0 && qc == 0)  af = (bf16x8)0;  // w==0 edge
        if (dx > 0 && mi == 3 && qc == 15) af = (bf16x8)0;  // w==63 edge
#pragma unroll
        for (int ni = 0; ni < 8; ++ni)
          acc[mi][ni] = __builtin_amdgcn_mfma_f32_16x16x32_bf16(af, bf[ni], acc[mi][ni], 0, 0, 0);
      }
      asm volatile("s_waitcnt vmcnt(0)" ::: "memory");
      __syncthreads();
    }
  }

  if (!nchw) {
    ushort (*olds)[264] = (ushort(*)[264])smem;
#pragma unroll
    for (int mi = 0; mi < 4; ++mi) {
      int p = wm * 64 + mi * 16 + grp * 4;
#pragma unroll
      for (int ni = 0; ni < 8; ++ni) {
        int c = wn * 128 + ni * 16 + qc;
        float bv = bias_s[c];
#pragma unroll
        for (int r = 0; r < 4; ++r)
          olds[p + r][c] = f2bf(fmaxf(acc[mi][ni][r] + bv, 0.f) * oscale);
      }
    }
    __syncthreads();
    ushort* dst = outT + ((size_t)b * 4096 + n0) * 256;
#pragma unroll
    for (int k = 0; k < 16; ++k) {
      int idx = t + k * 256;
      int r = idx >> 5, u = idx & 31;
      *(u16x8*)&dst[(size_t)r * 256 + u * 8] = *(const u16x8*)&olds[r][u * 8];
    }
  } else {
    ushort (*oldsT)[136] = (ushort(*)[136])smem;
#pragma unroll
    for (int mi = 0; mi < 4; ++mi) {
      int p = wm * 64 + mi * 16 + grp * 4;
#pragma unroll
      for (int ni = 0; ni < 8; ++ni) {
        int c = wn * 128 + ni * 16 + qc;
        float bv = bias_s[c];
        ushort4 pk;
        pk.x = f2bf(fmaxf(acc[mi][ni][0] + bv, 0.f) * oscale);
        pk.y = f2bf(fmaxf(acc[mi][ni][1] + bv, 0.f) * oscale);
        pk.z = f2bf(fmaxf(acc[mi][ni][2] + bv, 0.f) * oscale);
        pk.w = f2bf(fmaxf(acc[mi][ni][3] + bv, 0.f) * oscale);
        *(ushort4*)&oldsT[c][p] = pk;
      }
    }
    __syncthreads();
    ushort* dst = outV + (size_t)b * 256 * 4096 + n0;
#pragma unroll
    for (int k = 0; k < 16; ++k) {
      int idx = t + k * 256;
      int c = idx >> 4, u = idx & 15;
      *(u16x8*)&dst[(size_t)c * 4096 + u * 8] = *(const u16x8*)&oldsT[c][u * 8];
    }
  }
}

// ---------------- K4: bf16 MFMA flash attention + residual + BN partials ---
// 512 thr = 8 waves = 2 waves/SIMD, 16 q/wave, KVBLK=64 (round-9 main loop,
// measured 218us; round-11 BN epilogue -> 200us). BN partials: butterfly
// within 32-lane group (c uniform) -> plain LDS store (bijective
// (w,halfgrp,iter)->channel map, NO atomics in loop) -> 512 global atomics.
// LDS: kbuf[2][64][256] 64K | vbuf[2][256][64] 64K | plds[128][64] 16K = 144K.
__global__ __launch_bounds__(512, 2) void k_attn(
    const ushort* __restrict__ q_t, const ushort* __restrict__ k_t,
    const ushort* __restrict__ v_t, const float* __restrict__ x,
    float* __restrict__ y, float* __restrict__ gstat)
{
  extern __shared__ unsigned char smem[];
  ushort* kbf0 = (ushort*)smem;                   // [64][256]
  ushort* kbf1 = (ushort*)(smem + 32768);
  ushort* vbf0 = (ushort*)(smem + 65536);         // [256][64]
  ushort* vbf1 = (ushort*)(smem + 98304);
  ushort* pl   = (ushort*)(smem + 131072);        // [128][64]

  const int tid = threadIdx.x, lane = tid & 63, w = tid >> 6;
  const int grp = lane >> 4, qc = lane & 15, xr = qc & 7;
  const int b = blockIdx.y, q0 = blockIdx.x * 128;
  const int wbase = tid & ~63;

  // per-lane DMA source offsets (ushort units); swizzles match LDS reads
  int offk[4], offv[4];
#pragma unroll
  for (int k = 0; k < 4; ++k) {
    int i = k * 512 + tid;
    int j = i >> 5, s = i & 31;                 // K: 64 rows x 32 granules
    offk[k] = j * 256 + ((s ^ (j & 7)) << 3);
    int d = i >> 3, s2 = i & 7;                 // V: 256 rows x 8 granules
    offv[k] = d * 4096 + ((s2 ^ (d & 7)) << 3);
  }
  const ushort* kT = k_t + (size_t)b * 4096 * 256;
  const ushort* vT = v_t + (size_t)b * 256 * 4096;

  // Q fragments (1/16*log2e pre-folded in q_t); wave owns q = q0+w*16+qc
  bf16x8 qf[8];
  {
    const ushort* qrow = q_t + ((size_t)b * 4096 + q0 + w * 16 + qc) * 256;
#pragma unroll
    for (int dc = 0; dc < 8; ++dc)
      qf[dc] = *(const bf16x8*)&qrow[dc * 32 + grp * 8];
  }

  f32x4 o[16];
#pragma unroll
  for (int dt = 0; dt < 16; ++dt) o[dt] = f32x4{0.f, 0.f, 0.f, 0.f};
  float m_run = -1e30f, lp = 0.f;

  auto stage = [&](const ushort* kp, const ushort* vp, ushort* kb, ushort* vb) {
#pragma unroll
    for (int k = 0; k < 4; ++k)
      dma16(kp + offk[k], kb + (size_t)(k * 512 + wbase) * 8);
#pragma unroll
    for (int k = 0; k < 4; ++k)
      dma16(vp + offv[k], vb + (size_t)(k * 512 + wbase) * 8);
  };

  stage(kT, vT, kbf0, vbf0);
  kT += 16384; vT += 64;
  asm volatile("s_waitcnt vmcnt(0)" ::: "memory");
  __syncthreads();

  ushort* prow = pl + (size_t)(w * 16 + qc) * 64;
  int po[4], pslot[2];
#pragma unroll
  for (int kt = 0; kt < 4; ++kt)
    po[kt] = (((2 * kt + (grp >> 1)) ^ xr) << 3) + ((grp & 1) << 2);
#pragma unroll
  for (int kc = 0; kc < 2; ++kc)
    pslot[kc] = ((kc * 4 + grp) ^ xr) << 3;

  for (int t = 0; t < 64; ++t) {
    ushort* kb = (t & 1) ? kbf1 : kbf0;
    ushort* vb = (t & 1) ? vbf1 : vbf0;
    if (t < 63) {
      stage(kT, vT, (t & 1) ? kbf0 : kbf1, (t & 1) ? vbf0 : vbf1);
      kT += 16384; vT += 64;
    }

    // ---- S^T = K * Q^T (K-frags batch-loaded before MFMAs) ----
    f32x4 st[4];
    __builtin_amdgcn_s_setprio(1);
#pragma unroll
    for (int kt = 0; kt < 4; ++kt) {
      const int row = (kt * 16 + qc) * 256;
      bf16x8 ka8[8];
#pragma unroll
      for (int dc = 0; dc < 8; ++dc)
        ka8[dc] = *(const bf16x8*)&kb[row + (((dc * 4 + grp) ^ xr) << 3)];
      f32x4 a = f32x4{0.f, 0.f, 0.f, 0.f};
#pragma unroll
      for (int dc = 0; dc < 8; ++dc)
        a = __builtin_amdgcn_mfma_f32_16x16x32_bf16(ka8[dc], qf[dc], a, 0, 0, 0);
      st[kt] = a;
    }
    __builtin_amdgcn_s_setprio(0);

    // ---- online softmax (exp2 domain, defer-max, deferred l) ----
    float pmax = fmaxf(
        fmaxf(fmaxf(st[0][0], st[0][1]), fmaxf(st[0][2], st[0][3])),
        fmaxf(fmaxf(st[1][0], st[1][1]), fmaxf(st[1][2], st[1][3])));
    pmax = fmaxf(pmax, fmaxf(
        fmaxf(fmaxf(st[2][0], st[2][1]), fmaxf(st[2][2], st[2][3])),
        fmaxf(fmaxf(st[3][0], st[3][1]), fmaxf(st[3][2], st[3][3]))));
    pmax = fmaxf(pmax, __shfl_xor(pmax, 16));
    pmax = fmaxf(pmax, __shfl_xor(pmax, 32));
    if (pmax - m_run > 11.5f) {
      float mn = fmaxf(m_run, pmax);
      float al = exp2f(m_run - mn);
      m_run = mn; lp *= al;
#pragma unroll
      for (int dt = 0; dt < 16; ++dt) {
        o[dt][0] *= al; o[dt][1] *= al; o[dt][2] *= al; o[dt][3] *= al;
      }
    }
#pragma unroll
    for (int kt = 0; kt < 4; ++kt) {
      float p0 = exp2f(st[kt][0] - m_run);
      float p1 = exp2f(st[kt][1] - m_run);
      float p2 = exp2f(st[kt][2] - m_run);
      float p3 = exp2f(st[kt][3] - m_run);
      lp += (p0 + p1) + (p2 + p3);
      uint2 pk = { cvtpk(p0, p1), cvtpk(p2, p3) };
      *(uint2*)&prow[po[kt]] = pk;
    }

    // ---- r^T += V^T * P (V-frags double-buffered in 4-dt batches) ----
    bf16x8 pb0 = *(const bf16x8*)&prow[pslot[0]];
    bf16x8 pb1 = *(const bf16x8*)&prow[pslot[1]];
    bf16x8 vaA[8], vaB[8];
#pragma unroll
    for (int j = 0; j < 8; ++j) {
      int dt = j >> 1;
      vaA[j] = *(const bf16x8*)&vb[(dt * 16 + qc) * 64 + pslot[j & 1]];
    }
    __builtin_amdgcn_s_setprio(1);
#pragma unroll
    for (int bt = 0; bt < 4; ++bt) {
      const bf16x8* cur = (bt & 1) ? vaB : vaA;
      bf16x8* nxt = (bt & 1) ? vaA : vaB;
      if (bt < 3) {
#pragma unroll
        for (int j = 0; j < 8; ++j) {
          int dt = (bt + 1) * 4 + (j >> 1);
          nxt[j] = *(const bf16x8*)&vb[(dt * 16 + qc) * 64 + pslot[j & 1]];
        }
      }
#pragma unroll
      for (int j2 = 0; j2 < 4; ++j2) {
        int dt = bt * 4 + j2;
        o[dt] = __builtin_amdgcn_mfma_f32_16x16x32_bf16(cur[2 * j2],     pb0, o[dt], 0, 0, 0);
        o[dt] = __builtin_amdgcn_mfma_f32_16x16x32_bf16(cur[2 * j2 + 1], pb1, o[dt], 0, 0, 0);
      }
    }
    __builtin_amdgcn_s_setprio(0);

    asm volatile("s_waitcnt vmcnt(0)" ::: "memory");
    __syncthreads();  // next tile's DMA landed; buffers swappable
  }

  // ---- epilogue: reduce l, relay r^T via LDS, y = r + x, BN partials -----
  lp += __shfl_xor(lp, 16);
  lp += __shfl_xor(lp, 32);
  float inv = 1.f / lp;

  float (*obuf)[132] = (float(*)[132])smem;      // [256 d][128 q + pad] 135168B
  float* part1 = (float*)(smem + 135168);        // [256]
  float* part2 = (float*)(smem + 136192);        // [256]
#pragma unroll
  for (int dt = 0; dt < 16; ++dt)
#pragma unroll
    for (int r = 0; r < 4; ++r)
      obuf[dt * 16 + grp * 4 + r][w * 16 + qc] = o[dt][r] * inv;
  __syncthreads();

  const float* xb = x + (size_t)b * 256 * 4096 + q0;
  float*       yb = y + (size_t)b * 256 * 4096 + q0;
#pragma unroll
  for (int k = 0; k < 16; ++k) {
    int i = tid + k * 512;
    int c = i >> 5, f4 = (i & 31) << 2;
    float4 xr4 = *(const float4*)&xb[(size_t)c * 4096 + f4];
    float4 rv = *(const float4*)&obuf[c][f4];
    rv.x += xr4.x; rv.y += xr4.y; rv.z += xr4.z; rv.w += xr4.w;
    *(float4*)&yb[(size_t)c * 4096 + f4] = rv;
    // BN partials: c uniform across each 32-lane group -> butterfly, then
    // lane0 plain-stores part[c] (each (w,halfgrp,k) owns a unique c).
    float ls1 = (rv.x + rv.y) + (rv.z + rv.w);
    float ls2 = (rv.x * rv.x + rv.y * rv.y) + (rv.z * rv.z + rv.w * rv.w);
#pragma unroll
    for (int sh = 1; sh <= 16; sh <<= 1) {
      ls1 += __shfl_xor(ls1, sh);
      ls2 += __shfl_xor(ls2, sh);
    }
    if ((tid & 31) == 0) { part1[c] = ls1; part2[c] = ls2; }
  }
  __syncthreads();
  if (tid < 256) {
    atomicAdd(&gstat[tid], part1[tid]);
    atomicAdd(&gstat[256 + tid], part2[tid]);
  }
}

// ---------------- K5: BN finalize + apply in place (fused) -----------------
__global__ __launch_bounds__(256) void k_bnapply(
    float* __restrict__ y, const float* __restrict__ gstat,
    const float* __restrict__ gamma, const float* __restrict__ beta)
{
  __shared__ float sc_s[256], sh_s[256];
  {
    const int c = threadIdx.x;
    float mean = gstat[c] * (1.f / 32768.f);
    float var  = gstat[256 + c] * (1.f / 32768.f) - mean * mean;
    float inv  = rsqrtf(var + 1e-5f);
    float g = gamma[c] * inv;
    sc_s[c] = g;
    sh_s[c] = beta[c] - mean * g;
  }
  __syncthreads();
  const int total4 = 8 * 256 * 1024;
  for (int i = blockIdx.x * 256 + threadIdx.x; i < total4; i += gridDim.x * 256) {
    int c = (i >> 10) & 255;
    float sc = sc_s[c], sh = sh_s[c];
    float4 v = ((const float4*)y)[i];
    v.x = fmaf(v.x, sc, sh);
    v.y = fmaf(v.y, sc, sh);
    v.z = fmaf(v.z, sc, sh);
    v.w = fmaf(v.w, sc, sh);
    ((float4*)y)[i] = v;
  }
}

// ---------------------------------------------------------------------------
extern "C" void kernel_launch(void* const* d_in, const int* in_sizes, int n_in,
                              void* d_out, int out_size, void* d_ws, size_t ws_size,
                              hipStream_t stream) {
  const float* x     = (const float*)d_in[0];
  const float* wq    = (const float*)d_in[1];
  const float* bq    = (const float*)d_in[2];
  const float* wkv   = (const float*)d_in[3];
  const float* bkv   = (const float*)d_in[4];
  const float* gamma = (const float*)d_in[5];
  const float* beta  = (const float*)d_in[6];
  float* out = (float*)d_out;

  ushort* xt  = (ushort*)d_ws;            // 8*4224*256 = 8650752
  ushort* wt3 = xt  + (size_t)8650752;    // 9*512*256 = 1179648
  ushort* wt1 = wt3 + (size_t)1179648;    // 256*256   = 65536
  ushort* q_t = wt1 + (size_t)65536;      // 8388608
  ushort* k_t = q_t + (size_t)8388608;
  ushort* v_t = k_t + (size_t)8388608;
  float* gstat = (float*)(v_t + (size_t)8388608);  // 512 floats

  hipMemsetAsync(gstat, 0, 2048, stream);

  k_xt<<<dim3(66, 4, 8), 256, 0, stream>>>(x, xt);
  k_wprep<<<dim3(512), 256, 0, stream>>>(wkv, wt3, 9, 512);
  k_wprep<<<dim3(256), 256, 0, stream>>>(wq, wt1, 1, 256);

  const int conv_smem = 69632;
  hipFuncSetAttribute(reinterpret_cast<const void*>(k_conv),
                      hipFuncAttributeMaxDynamicSharedMemorySize, conv_smem);
  // q = relu(conv1x1) * (1/16 * log2e) -> token-major (exp2-domain softmax)
  k_conv<<<dim3(32, 1, 8), 256, conv_smem, stream>>>(
      xt, wt1, bq, q_t, nullptr, 1, 256, 0.0625f * 1.44269504f);
  k_conv<<<dim3(32, 2, 8), 256, conv_smem, stream>>>(
      xt, wt3, bkv, k_t, v_t, 9, 512, 1.0f);

  const int attn_smem = 147456;  // 144 KB
  hipFuncSetAttribute(reinterpret_cast<const void*>(k_attn),
                      hipFuncAttributeMaxDynamicSharedMemorySize, attn_smem);
  k_attn<<<dim3(32, 8), 512, attn_smem, stream>>>(q_t, k_t, v_t, x, out, gstat);

  k_bnapply<<<dim3(2048), 256, 0, stream>>>(out, gstat, gamma, beta);
}